// Round 1
// baseline (1077.973 us; speedup 1.0000x reference)
//
#include <hip/hip_runtime.h>
#include <cstdint>

#define K_TOP 30

// Monotone map float -> uint32 (order-preserving total order).
__device__ __forceinline__ unsigned mapf(float f) {
  int b = __float_as_int(f);
  return (unsigned)b ^ (unsigned)((b >> 31) | 0x80000000);
}
__device__ __forceinline__ float unmapf(unsigned u) {
  int b = (u & 0x80000000u) ? (int)(u ^ 0x80000000u) : (int)~u;
  return __int_as_float(b);
}

__device__ __forceinline__ int countGreater(const unsigned (&u)[16], unsigned T) {
  int c = 0;
#pragma unroll
  for (int e = 0; e < 16; ++e)
    c += (int)__popcll(__ballot(u[e] > T));
  return c;
}

// One wave computes top-30 of a 1024-float row.
// On return: lanes 0..29 hold (val, col) in descending value order.
__device__ __forceinline__ void topk_row(const float4* __restrict__ rp, int lane,
                                         volatile unsigned* ldsU,
                                         volatile unsigned* ldsC,
                                         float& val, unsigned& col) {
  unsigned u[16];
#pragma unroll
  for (int q = 0; q < 4; ++q) {
    float4 v = rp[q * 64 + lane];
    u[q * 4 + 0] = mapf(v.x);
    u[q * 4 + 1] = mapf(v.y);
    u[q * 4 + 2] = mapf(v.z);
    u[q * 4 + 3] = mapf(v.w);
  }

  // Find threshold T with count(u > T) in [30, 64].
  // First guess map(1.70f): works for ~99% of N(0,1) rows; else binary search.
  unsigned lo = 0u, hi = 0xFFFFFFFFu;
  unsigned T = 0xBFD9999Au;  // mapf(1.70f)
  int c = countGreater(u, T);
  int it = 0;
  while ((c < K_TOP || c > 64) && it < 40) {
    if (c >= K_TOP) lo = T; else hi = T;
    T = lo + ((hi - lo) >> 1);
    c = countGreater(u, T);
    ++it;
  }

  // Compact candidates (u > T) into per-wave LDS slots [0, c).
  int base = 0;
#pragma unroll
  for (int e = 0; e < 16; ++e) {
    bool p = u[e] > T;
    unsigned long long m = __ballot(p);
    int below = __builtin_amdgcn_mbcnt_hi((unsigned)(m >> 32),
                  __builtin_amdgcn_mbcnt_lo((unsigned)m, 0));
    int dest = base + below;
    if (p) {
      if (dest > 63) dest = 63;  // degenerate-duplicate safety clamp
      ldsU[dest] = u[e];
      ldsC[dest] = (unsigned)((e >> 2) * 256 + lane * 4 + (e & 3));
    }
    base += (int)__popcll(m);
  }
  int cc = base < 64 ? base : 64;

  // Intra-wave LDS is in-order; reads below depend on writes above (same arrays).
  unsigned mu = 0u, mc = 0u;
  if (lane < cc) { mu = ldsU[lane]; mc = ldsC[lane]; }

  // Bitonic sort 64 lanes, descending by mu, payload mc.
#pragma unroll
  for (int k = 2; k <= 64; k <<= 1) {
#pragma unroll
    for (int j = k >> 1; j > 0; j >>= 1) {
      unsigned u2 = __shfl_xor(mu, j);
      unsigned c2 = __shfl_xor(mc, j);
      bool lower = (lane & j) == 0;
      bool blockDesc = (lane & k) == 0;
      bool takeMax = (lower == blockDesc);
      bool keep = takeMax ? !(mu < u2) : !(mu > u2);
      mu = keep ? mu : u2;
      mc = keep ? mc : c2;
    }
  }
  val = unmapf(mu);
  col = mc;
}

__global__ __launch_bounds__(256) void TopKAccuracy_kernel(
    const float* __restrict__ pred, const float* __restrict__ target,
    float* __restrict__ out, int B, float accScale, float diffScale) {
  __shared__ unsigned sU[4][64];
  __shared__ unsigned sC[4][64];
  __shared__ float sD[4];
  __shared__ int sM[4];

  const int w = threadIdx.x >> 6;
  const int lane = threadIdx.x & 63;
  const int gw = blockIdx.x * 4 + w;
  const int W = gridDim.x * 4;

  float accD = 0.0f;
  int accM = 0;

  for (int row = gw; row < B; row += W) {
    const float4* rp = reinterpret_cast<const float4*>(pred + (size_t)row * 1024);
    const float4* rt = reinterpret_cast<const float4*>(target + (size_t)row * 1024);
    float vp, vt;
    unsigned pc, tc;
    topk_row(rp, lane, sU[w], sC[w], vp, pc);
    topk_row(rt, lane, sU[w], sC[w], vt, tc);

    // diff: positional |v_pred - v_topk| over k=0..29
    float d = (lane < K_TOP) ? fabsf(vp - vt) : 0.0f;
#pragma unroll
    for (int j = 32; j > 0; j >>= 1) d += __shfl_xor(d, j);
    accD += d;

    // intersection count of index sets
    int found = 0;
#pragma unroll
    for (int j = 0; j < K_TOP; ++j) {
      unsigned tj = __shfl(tc, j);
      found |= (pc == tj) ? 1 : 0;
    }
    unsigned long long mm = __ballot(found && (lane < K_TOP));
    accM += (int)__popcll(mm);
  }

  if (lane == 0) { sD[w] = accD; sM[w] = accM; }
  __syncthreads();
  if (threadIdx.x == 0) {
    float td = sD[0] + sD[1] + sD[2] + sD[3];
    int tm = sM[0] + sM[1] + sM[2] + sM[3];
    atomicAdd(&out[0], (float)tm * accScale);
    atomicAdd(&out[1], td * diffScale);
  }
}

__global__ void zero_kernel(float* out) {
  if (threadIdx.x < 2) out[threadIdx.x] = 0.0f;
}

extern "C" void kernel_launch(void* const* d_in, const int* in_sizes, int n_in,
                              void* d_out, int out_size, void* d_ws, size_t ws_size,
                              hipStream_t stream) {
  const float* pred = (const float*)d_in[0];
  const float* target = (const float*)d_in[1];
  float* out = (float*)d_out;
  const int C = 1024;
  const int B = in_sizes[0] / C;
  const float accScale = 1.0f / (30.0f * (float)B);
  const float diffScale = 1.0f / 30.0f;

  zero_kernel<<<1, 64, 0, stream>>>(out);
  const int blocks = 2048;  // 8192 waves -> 16 rows/wave at B=131072
  TopKAccuracy_kernel<<<blocks, 256, 0, stream>>>(pred, target, out, B, accScale, diffScale);
}